// Round 3
// baseline (930.382 us; speedup 1.0000x reference)
//
#include <hip/hip_runtime.h>

#define NN 512
#define BATCH 256
#define T 8
#define SENT 0xBF80000000000000ull

// ---- u64 DPP max reduce to lane 63 (VALU-only, branch-free) ----
#define DPP_MAX64(k, ctrl) do {                                               \
    int _lo = (int)(unsigned)(k); int _hi = (int)((k) >> 32);                 \
    int _olo = __builtin_amdgcn_update_dpp(_lo, _lo, ctrl, 0xf, 0xf, false);  \
    int _ohi = __builtin_amdgcn_update_dpp(_hi, _hi, ctrl, 0xf, 0xf, false);  \
    unsigned long long _o =                                                   \
        ((unsigned long long)(unsigned)_ohi << 32) | (unsigned)_olo;          \
    if (_o > (k)) (k) = _o;                                                   \
} while (0)

#define WAVE_MAX64(k) do {                                                    \
    DPP_MAX64(k, 0x111); DPP_MAX64(k, 0x112); DPP_MAX64(k, 0x114);            \
    DPP_MAX64(k, 0x118); DPP_MAX64(k, 0x142); DPP_MAX64(k, 0x143);            \
} while (0)

__device__ __forceinline__ unsigned long long readlane64(unsigned long long k, int l) {
    unsigned lo = (unsigned)__builtin_amdgcn_readlane((int)(unsigned)k, l);
    unsigned hi = (unsigned)__builtin_amdgcn_readlane((int)(k >> 32), l);
    return ((unsigned long long)hi << 32) | lo;
}

// register-resident column-alive lookup (cndmask cascade, no memory)
#define ALIVE(c, res) do { const int _w = (c) >> 6;                           \
    unsigned long long _x = am0;                                              \
    _x = (_w == 1) ? am1 : _x; _x = (_w == 2) ? am2 : _x;                     \
    _x = (_w == 3) ? am3 : _x; _x = (_w == 4) ? am4 : _x;                     \
    _x = (_w == 5) ? am5 : _x; _x = (_w == 6) ? am6 : _x;                     \
    _x = (_w == 7) ? am7 : _x;                                                \
    (res) = (_x >> ((c) & 63)) & 1ull; } while (0)

#define KILLCOL(c) do { const unsigned long long _m = ~(1ull << ((c) & 63));  \
    switch ((c) >> 6) {                                                       \
        case 0: am0 &= _m; break; case 1: am1 &= _m; break;                   \
        case 2: am2 &= _m; break; case 3: am3 &= _m; break;                   \
        case 4: am4 &= _m; break; case 5: am5 &= _m; break;                   \
        case 6: am6 &= _m; break; default: am7 &= _m; break;                  \
    } } while (0)

// ---------------------------------------------------------------------------
// Kernel 1: per-row top-T (desc value, asc col) -> first NN*T u64 of each
// batch's out region (staged to LDS by kernel 2 before outputs land there).
// ---------------------------------------------------------------------------
__global__ __launch_bounds__(256) void build_top(const float* __restrict__ s,
                                                 float* __restrict__ out) {
    const int wave = threadIdx.x >> 6;
    const int lane = threadIdx.x & 63;
    const int row_g = blockIdx.x * 4 + wave;
    const int b = row_g >> 9;
    const int r = row_g & (NN - 1);
    const float* rp = s + (size_t)row_g * NN;
    unsigned long long* dst =
        (unsigned long long*)(out + (size_t)b * NN * NN) + (size_t)r * T;

    const float4 a  = *(const float4*)(rp + 4 * lane);
    const float4 c2 = *(const float4*)(rp + 256 + 4 * lane);
    float v[8] = {a.x, a.y, a.z, a.w, c2.x, c2.y, c2.z, c2.w};

    #pragma unroll
    for (int t = 0; t < T; ++t) {
        // key = (val_bits+1)<<9 | (511-col): max val, then min col
        unsigned long long k2[8];
        #pragma unroll
        for (int i = 0; i < 8; ++i) {
            const int col = (i < 4) ? (4 * lane + i) : (256 + 4 * lane + (i - 4));
            k2[i] = (v[i] < 0.0f) ? 0ull
                  : (((unsigned long long)((unsigned)__float_as_int(v[i]) + 1u) << 9)
                     | (unsigned)(511 - col));
        }
        unsigned long long t0 = k2[0] > k2[1] ? k2[0] : k2[1];
        unsigned long long t1 = k2[2] > k2[3] ? k2[2] : k2[3];
        unsigned long long t2 = k2[4] > k2[5] ? k2[4] : k2[5];
        unsigned long long t3 = k2[6] > k2[7] ? k2[6] : k2[7];
        t0 = t0 > t1 ? t0 : t1;  t2 = t2 > t3 ? t2 : t3;
        unsigned long long bk = t0 > t2 ? t0 : t2;
        WAVE_MAX64(bk);
        bk = readlane64(bk, 63);

        const int wcol = 511 - (int)(bk & 511);
        const unsigned vb = (unsigned)(bk >> 9) - 1u;
        if (lane == 0)
            dst[t] = ((unsigned long long)vb << 32) | (unsigned)wcol;

        const int owner = (wcol & 255) >> 2;
        const int slot  = ((wcol >> 8) << 2) | (wcol & 3);
        if (lane == owner) {
            #pragma unroll
            for (int i = 0; i < 8; ++i)
                if (i == slot) v[i] = -1.0f;
        }
    }
}

// ---------------------------------------------------------------------------
// Kernel 2: sequential greedy matching, one wave per batch element.
// All per-step state in registers: row-head keys (8/lane), column-alive
// mask (8 u64/lane, replicated). Candidate lists in LDS, walked only when
// a head's column dies; HBM fallback rebuild when a list exhausts.
// ---------------------------------------------------------------------------
__global__ __launch_bounds__(64) void greedy_match(const float* __restrict__ s,
                                                   float* __restrict__ out) {
    __shared__ unsigned long long lst[NN][T];   // 32 KB

    const int b = blockIdx.x;
    const int lane = threadIdx.x;
    const float* sb = s + (size_t)b * NN * NN;
    float* ob = out + (size_t)b * NN * NN;

    // ---- stage candidate lists from out-region into LDS ----
    {
        const ulonglong2* src = (const ulonglong2*)ob;
        ulonglong2* dstl = (ulonglong2*)&lst[0][0];
        #pragma unroll
        for (int j = 0; j < (NN * T / 2) / 64; ++j)
            dstl[lane + 64 * j] = src[lane + 64 * j];
    }

    unsigned long long am0 = ~0ull, am1 = ~0ull, am2 = ~0ull, am3 = ~0ull,
                       am4 = ~0ull, am5 = ~0ull, am6 = ~0ull, am7 = ~0ull;

    // key = (val_bits+1)<<18 | (511-row)<<9 | col ; 0 = row dead
    unsigned long long key[8];
    int ptr[8];
    #pragma unroll
    for (int k = 0; k < 8; ++k) {
        const unsigned long long e = lst[lane + 64 * k][0];
        key[k] = (((e >> 32) + 1ull) << 18)
               | ((unsigned long long)(unsigned)(511 - lane - 64 * k) << 9)
               | (e & 511ull);
        ptr[k] = 0;
    }

    float* const obase0 = ob + 4 * lane;
    float* const obase1 = ob + 256 + 4 * lane;

    for (int step = 0; step < NN; ++step) {
        // ---- wave argmax over row-head keys (branch-free) ----
        unsigned long long t0 = key[0] > key[1] ? key[0] : key[1];
        unsigned long long t1 = key[2] > key[3] ? key[2] : key[3];
        unsigned long long t2 = key[4] > key[5] ? key[4] : key[5];
        unsigned long long t3 = key[6] > key[7] ? key[6] : key[7];
        t0 = t0 > t1 ? t0 : t1;  t2 = t2 > t3 ? t2 : t3;
        unsigned long long bk = t0 > t2 ? t0 : t2;
        WAVE_MAX64(bk);
        bk = readlane64(bk, 63);

        const int cstar = (int)(bk & 511);
        const int rstar = 511 - (int)((bk >> 9) & 511);

        // ---- write output row rstar ----
        float4 o0, o1;
        o0.x = (4 * lane + 0 == cstar) ? 1.0f : 0.0f;
        o0.y = (4 * lane + 1 == cstar) ? 1.0f : 0.0f;
        o0.z = (4 * lane + 2 == cstar) ? 1.0f : 0.0f;
        o0.w = (4 * lane + 3 == cstar) ? 1.0f : 0.0f;
        o1.x = (256 + 4 * lane + 0 == cstar) ? 1.0f : 0.0f;
        o1.y = (256 + 4 * lane + 1 == cstar) ? 1.0f : 0.0f;
        o1.z = (256 + 4 * lane + 2 == cstar) ? 1.0f : 0.0f;
        o1.w = (256 + 4 * lane + 3 == cstar) ? 1.0f : 0.0f;
        *(float4*)(obase0 + (size_t)rstar * NN) = o0;
        *(float4*)(obase1 + (size_t)rstar * NN) = o1;

        // ---- kill row + col ----
        #pragma unroll
        for (int k = 0; k < 8; ++k)
            if ((rstar >> 6) == k && (rstar & 63) == lane) key[k] = 0;
        KILLCOL(cstar);

        // ---- rescan rows whose head col just died (LDS walk, reg alive) ----
        unsigned need = 0;
        #pragma unroll
        for (int k = 0; k < 8; ++k)
            if (key[k] != 0 && (int)(key[k] & 511) == cstar) need |= 1u << k;

        unsigned fb = 0;
        if (__ballot(need != 0)) {
            #pragma unroll
            for (int k = 0; k < 8; ++k) {
                if (need & (1u << k)) {
                    const unsigned long long rowpart =
                        (unsigned long long)(unsigned)(511 - lane - 64 * k) << 9;
                    int p = ptr[k] + 1;
                    unsigned long long nk = 0;
                    while (p < T) {
                        const unsigned long long e1 = lst[lane + 64 * k][p];
                        const unsigned long long e2 =
                            (p + 1 < T) ? lst[lane + 64 * k][p + 1] : SENT;
                        const int v1 = (int)(e1 >> 32);
                        if (v1 < 0) { p = T; break; }
                        const int c1 = (int)e1 & 511;
                        unsigned long long ab; ALIVE(c1, ab);
                        if (ab) {
                            nk = (((unsigned long long)(unsigned)v1 + 1ull) << 18)
                               | rowpart | (unsigned)c1;
                            break;
                        }
                        ++p;
                        if (p >= T) break;
                        const int v2 = (int)(e2 >> 32);
                        if (v2 < 0) { p = T; break; }
                        const int c2i = (int)e2 & 511;
                        ALIVE(c2i, ab);
                        if (ab) {
                            nk = (((unsigned long long)(unsigned)v2 + 1ull) << 18)
                               | rowpart | (unsigned)c2i;
                            break;
                        }
                        ++p;
                    }
                    ptr[k] = p;
                    if (nk) key[k] = nk; else fb |= 1u << k;
                }
            }
        }

        // ---- rare fallback: HBM reload, rebuild top-4 into LDS ----
        if (__ballot(fb != 0)) {
            #pragma unroll
            for (int k = 0; k < 8; ++k) {
                unsigned long long mk = __ballot((fb >> k) & 1u);
                while (mk) {
                    const int lr = __builtin_ctzll(mk); mk &= mk - 1;
                    const int row = lr + 64 * k;
                    const float* rp = sb + (size_t)row * NN;
                    const float4 a  = *(const float4*)(rp + 4 * lane);
                    const float4 cc = *(const float4*)(rp + 256 + 4 * lane);
                    float cur[8] = {a.x, a.y, a.z, a.w, cc.x, cc.y, cc.z, cc.w};
                    #pragma unroll
                    for (int i = 0; i < 8; ++i) {
                        const int col = (i < 4) ? (4 * lane + i)
                                                : (256 + 4 * lane + (i - 4));
                        unsigned long long ab; ALIVE(col, ab);
                        if (!ab) cur[i] = -1.0f;
                    }
                    #pragma unroll
                    for (int j = 0; j < 4; ++j) {
                        unsigned long long k2[8];
                        #pragma unroll
                        for (int i = 0; i < 8; ++i) {
                            const int col = (i < 4) ? (4 * lane + i)
                                                    : (256 + 4 * lane + (i - 4));
                            k2[i] = (cur[i] < 0.0f) ? 0ull
                                  : (((unsigned long long)
                                        ((unsigned)__float_as_int(cur[i]) + 1u) << 9)
                                     | (unsigned)(511 - col));
                        }
                        unsigned long long u0 = k2[0] > k2[1] ? k2[0] : k2[1];
                        unsigned long long u1 = k2[2] > k2[3] ? k2[2] : k2[3];
                        unsigned long long u2 = k2[4] > k2[5] ? k2[4] : k2[5];
                        unsigned long long u3 = k2[6] > k2[7] ? k2[6] : k2[7];
                        u0 = u0 > u1 ? u0 : u1;  u2 = u2 > u3 ? u2 : u3;
                        unsigned long long bk2 = u0 > u2 ? u0 : u2;
                        WAVE_MAX64(bk2);
                        bk2 = readlane64(bk2, 63);

                        const int wcol = 511 - (int)(bk2 & 511);
                        const unsigned vb = (unsigned)(bk2 >> 9) - 1u;
                        if (lane == 0)
                            lst[row][j] = (bk2 == 0) ? SENT
                                : (((unsigned long long)vb << 32) | (unsigned)wcol);
                        if (j == 0 && lane == lr) {
                            key[k] = (bk2 == 0) ? 0ull
                                : (((unsigned long long)(vb + 1u) << 18)
                                   | ((unsigned long long)(unsigned)(511 - row) << 9)
                                   | (unsigned)wcol);
                            ptr[k] = 0;
                        }
                        if (bk2 != 0) {
                            const int owner = (wcol & 255) >> 2;
                            const int slot  = ((wcol >> 8) << 2) | (wcol & 3);
                            if (lane == owner) {
                                #pragma unroll
                                for (int i = 0; i < 8; ++i)
                                    if (i == slot) cur[i] = -1.0f;
                            }
                        }
                    }
                }
            }
        }
    }
}

extern "C" void kernel_launch(void* const* d_in, const int* in_sizes, int n_in,
                              void* d_out, int out_size, void* d_ws, size_t ws_size,
                              hipStream_t stream) {
    const float* s = (const float*)d_in[0];
    float* out = (float*)d_out;

    build_top<<<dim3(BATCH * NN / 4), dim3(256), 0, stream>>>(s, out);
    greedy_match<<<dim3(BATCH), dim3(64), 0, stream>>>(s, out);
}

// Round 4
// 686.107 us; speedup vs baseline: 1.3560x; 1.3560x over previous
//
#include <hip/hip_runtime.h>

#define NN 512
#define BATCH 256
#define T 8

typedef unsigned long long u64;
typedef unsigned u32;

// u64 max via f64 max: valid because all keys are positive f64 bit patterns
// (< 2^62, exponent field never all-ones) -> IEEE order == unsigned order.
__device__ __forceinline__ u64 fm(u64 a, u64 b) {
    return (u64)__double_as_longlong(fmax(__longlong_as_double((long long)a),
                                          __longlong_as_double((long long)b)));
}

#define DPP_FMAX64(k, ctrl) do {                                              \
    int _lo = (int)(u32)(k); int _hi = (int)((k) >> 32);                      \
    int _olo = __builtin_amdgcn_update_dpp(_lo, _lo, ctrl, 0xf, 0xf, false);  \
    int _ohi = __builtin_amdgcn_update_dpp(_hi, _hi, ctrl, 0xf, 0xf, false);  \
    u64 _o = ((u64)(u32)_ohi << 32) | (u32)_olo;                              \
    (k) = fm((k), _o);                                                        \
} while (0)

#define WAVE_FMAX64(k) do {                                                   \
    DPP_FMAX64(k, 0x111); DPP_FMAX64(k, 0x112); DPP_FMAX64(k, 0x114);         \
    DPP_FMAX64(k, 0x118); DPP_FMAX64(k, 0x142); DPP_FMAX64(k, 0x143);         \
} while (0)

__device__ __forceinline__ u64 readlane64(u64 k, int l) {
    u32 lo = (u32)__builtin_amdgcn_readlane((int)(u32)k, l);
    u32 hi = (u32)__builtin_amdgcn_readlane((int)(k >> 32), l);
    return ((u64)hi << 32) | lo;
}

// register-replicated column-alive lookup
#define ALIVE(c, res) do { const int _w = (c) >> 6;                           \
    u64 _x = am0;                                                             \
    _x = (_w == 1) ? am1 : _x; _x = (_w == 2) ? am2 : _x;                     \
    _x = (_w == 3) ? am3 : _x; _x = (_w == 4) ? am4 : _x;                     \
    _x = (_w == 5) ? am5 : _x; _x = (_w == 6) ? am6 : _x;                     \
    _x = (_w == 7) ? am7 : _x;                                                \
    (res) = (_x >> ((c) & 63)) & 1ull; } while (0)

// ---------------------------------------------------------------------------
// Kernel 1: per-row top-T (desc value, asc col) -> first NN*T u64 of each
// batch's out region (staged to LDS by kernel 2 before outputs land there).
// Entry format: val_bits<<32 | col.
// ---------------------------------------------------------------------------
__global__ __launch_bounds__(256) void build_top(const float* __restrict__ s,
                                                 float* __restrict__ out) {
    const int wave = threadIdx.x >> 6;
    const int lane = threadIdx.x & 63;
    const int row_g = blockIdx.x * 4 + wave;
    const int b = row_g >> 9;
    const int r = row_g & (NN - 1);
    const float* rp = s + (size_t)row_g * NN;
    u64* dst = (u64*)(out + (size_t)b * NN * NN) + (size_t)r * T;

    const float4 a  = *(const float4*)(rp + 4 * lane);
    const float4 c2 = *(const float4*)(rp + 256 + 4 * lane);

    // pack once: cand = (val_bits+1)<<9 | (511-col)  (max val, then min col)
    u64 kk0 = (((u64)__float_as_uint(a.x)  + 1) << 9) | (u32)(511 - (4*lane + 0));
    u64 kk1 = (((u64)__float_as_uint(a.y)  + 1) << 9) | (u32)(511 - (4*lane + 1));
    u64 kk2 = (((u64)__float_as_uint(a.z)  + 1) << 9) | (u32)(511 - (4*lane + 2));
    u64 kk3 = (((u64)__float_as_uint(a.w)  + 1) << 9) | (u32)(511 - (4*lane + 3));
    u64 kk4 = (((u64)__float_as_uint(c2.x) + 1) << 9) | (u32)(511 - (256 + 4*lane + 0));
    u64 kk5 = (((u64)__float_as_uint(c2.y) + 1) << 9) | (u32)(511 - (256 + 4*lane + 1));
    u64 kk6 = (((u64)__float_as_uint(c2.z) + 1) << 9) | (u32)(511 - (256 + 4*lane + 2));
    u64 kk7 = (((u64)__float_as_uint(c2.w) + 1) << 9) | (u32)(511 - (256 + 4*lane + 3));

    #pragma unroll
    for (int t = 0; t < T; ++t) {
        u64 m0 = fm(kk0, kk1), m1 = fm(kk2, kk3);
        u64 m2 = fm(kk4, kk5), m3 = fm(kk6, kk7);
        m0 = fm(m0, m1); m2 = fm(m2, m3);
        u64 bk = fm(m0, m2);
        WAVE_FMAX64(bk);
        bk = readlane64(bk, 63);

        const int wcol = 511 - (int)(bk & 511);
        const u32 vb = (u32)(bk >> 9) - 1u;
        if (lane == 0) dst[t] = ((u64)vb << 32) | (u32)wcol;

        const int owner = (wcol & 255) >> 2;
        const int slot  = ((wcol >> 8) << 2) | (wcol & 3);
        if (lane == owner) {
            kk0 = (slot == 0) ? 0 : kk0;  kk1 = (slot == 1) ? 0 : kk1;
            kk2 = (slot == 2) ? 0 : kk2;  kk3 = (slot == 3) ? 0 : kk3;
            kk4 = (slot == 4) ? 0 : kk4;  kk5 = (slot == 5) ? 0 : kk5;
            kk6 = (slot == 6) ? 0 : kk6;  kk7 = (slot == 7) ? 0 : kk7;
        }
    }
}

// ---------------------------------------------------------------------------
// Kernel 2: sequential greedy matching, one wave per batch element.
// Row-head keys live in LDS:  key = (val_bits+1)<<32 | (511-row)<<16
//                                   | ptr<<9 | col        (0 = row dead)
// Column-alive mask replicated in registers (am0..am7).
// Slot j of a lane owns row ROWJ(j) = 128*(j>>1) + 2*lane + (j&1).
// ---------------------------------------------------------------------------
#define ROWJ(j) (128 * ((j) >> 1) + 2 * lane + ((j) & 1))

__global__ __launch_bounds__(64) void greedy_match(const float* __restrict__ s,
                                                   float* __restrict__ out) {
    __shared__ __align__(16) u64 lst[NN][T];   // 32 KB
    __shared__ __align__(16) u64 keys[NN];     // 4 KB

    const int b = blockIdx.x;
    const int lane = threadIdx.x;
    const float* sb = s + (size_t)b * NN * NN;
    float* ob = out + (size_t)b * NN * NN;

    // ---- stage candidate lists from out-region into LDS ----
    {
        const ulonglong2* src = (const ulonglong2*)ob;
        ulonglong2* dstl = (ulonglong2*)&lst[0][0];
        #pragma unroll
        for (int j = 0; j < 32; ++j)
            dstl[lane + 64 * j] = src[lane + 64 * j];
    }

    u64 am0 = ~0ull, am1 = ~0ull, am2 = ~0ull, am3 = ~0ull,
        am4 = ~0ull, am5 = ~0ull, am6 = ~0ull, am7 = ~0ull;

    // ---- initial keys (regs + LDS) ----
    u64 k0, k1, k2, k3, k4, k5, k6, k7;
#define INITK(j, KR) do {                                                     \
        const int r_ = ROWJ(j);                                               \
        const u64 e_ = lst[r_][0];                                            \
        KR = (((e_ >> 32) + 1ull) << 32) | ((u64)(u32)(511 - r_) << 16)       \
             | (e_ & 511ull);                                                 \
        keys[r_] = KR;                                                        \
    } while (0)
    INITK(0, k0); INITK(1, k1); INITK(2, k2); INITK(3, k3);
    INITK(4, k4); INITK(5, k5); INITK(6, k6); INITK(7, k7);

    for (int step = 0; step < NN; ++step) {
        // ---- wave argmax over all 512 keys ----
        u64 m0 = fm(k0, k1), m1 = fm(k2, k3), m2 = fm(k4, k5), m3 = fm(k6, k7);
        m0 = fm(m0, m1); m2 = fm(m2, m3);
        u64 bk = fm(m0, m2);
        WAVE_FMAX64(bk);
        bk = readlane64(bk, 63);

        const int cstar = (int)(bk & 511);
        const int rstar = 511 - (int)((bk >> 16) & 511);

        // ---- kill row (LDS) ----
        if (lane == 0) keys[rstar] = 0;

        // ---- kill col (register masks, uniform select) ----
        {
            const int cw = cstar >> 6;
            const u64 nb = ~(1ull << (cstar & 63));
            am0 = (cw == 0) ? (am0 & nb) : am0;  am1 = (cw == 1) ? (am1 & nb) : am1;
            am2 = (cw == 2) ? (am2 & nb) : am2;  am3 = (cw == 3) ? (am3 & nb) : am3;
            am4 = (cw == 4) ? (am4 & nb) : am4;  am5 = (cw == 5) ? (am5 & nb) : am5;
            am6 = (cw == 6) ? (am6 & nb) : am6;  am7 = (cw == 7) ? (am7 & nb) : am7;
        }

        // ---- which of my rows point at the dead col? ----
        u32 pend = 0;
        if (k0 > 511ull && (u32)(k0 & 511) == (u32)cstar) pend |= 1u;
        if (k1 > 511ull && (u32)(k1 & 511) == (u32)cstar) pend |= 2u;
        if (k2 > 511ull && (u32)(k2 & 511) == (u32)cstar) pend |= 4u;
        if (k3 > 511ull && (u32)(k3 & 511) == (u32)cstar) pend |= 8u;
        if (k4 > 511ull && (u32)(k4 & 511) == (u32)cstar) pend |= 16u;
        if (k5 > 511ull && (u32)(k5 & 511) == (u32)cstar) pend |= 32u;
        if (k6 > 511ull && (u32)(k6 & 511) == (u32)cstar) pend |= 64u;
        if (k7 > 511ull && (u32)(k7 & 511) == (u32)cstar) pend |= 128u;
        // exclude the just-matched row (regs are stale vs LDS)
        {
            const int rowner = (rstar >> 1) & 63;
            const int rslot  = ((rstar >> 7) << 1) | (rstar & 1);
            if (lane == rowner) pend &= ~(1u << rslot);
        }

        u32 fb = 0;
#define RESCAN(j, KR) do {                                                    \
        if (pend & (1u << (j))) {                                             \
            const int r_ = ROWJ(j);                                           \
            int p_ = (int)(((KR) >> 9) & 15) + 1;                             \
            u64 nk_ = 0;                                                      \
            while (p_ < T) {                                                  \
                const u64 e_ = lst[r_][p_];                                   \
                const int c_ = (int)(e_ & 511);                               \
                u64 ab_; ALIVE(c_, ab_);                                      \
                if (ab_) { nk_ = (((e_ >> 32) + 1ull) << 32)                  \
                               | ((u64)(u32)(511 - r_) << 16)                 \
                               | ((u64)(u32)p_ << 9) | (u32)c_; break; }      \
                ++p_;                                                         \
            }                                                                 \
            if (nk_) keys[r_] = nk_; else fb |= 1u << (j);                    \
        }                                                                     \
    } while (0)
        if (__ballot(pend != 0)) {
            RESCAN(0, k0); RESCAN(1, k1); RESCAN(2, k2); RESCAN(3, k3);
            RESCAN(4, k4); RESCAN(5, k5); RESCAN(6, k6); RESCAN(7, k7);
        }

        // ---- rare fallback: HBM reload of one row, top-1 among alive cols ----
#define FBJ(j) do {                                                           \
        u64 mk_ = __ballot((fb >> (j)) & 1u);                                 \
        while (mk_) {                                                         \
            const int l_ = (int)__builtin_ctzll(mk_); mk_ &= mk_ - 1;         \
            const int r_ = 128 * ((j) >> 1) + 2 * l_ + ((j) & 1);             \
            const float* rp_ = sb + (size_t)r_ * NN;                          \
            const float4 fa_ = *(const float4*)(rp_ + 4 * lane);              \
            const float4 fb_ = *(const float4*)(rp_ + 256 + 4 * lane);        \
            const int sh_ = (4 * lane) & 63; const int w_ = lane >> 4;        \
            u64 xlo_ = (w_ == 0) ? am0 : (w_ == 1) ? am1 : (w_ == 2) ? am2 : am3; \
            u64 xhi_ = (w_ == 0) ? am4 : (w_ == 1) ? am5 : (w_ == 2) ? am6 : am7; \
            const u32 al8_ = ((u32)(xlo_ >> sh_) & 0xFu)                      \
                           | (((u32)(xhi_ >> sh_) & 0xFu) << 4);              \
            u64 c0_ = (al8_ & 1u)   ? ((((u64)__float_as_uint(fa_.x) + 1) << 9) | (u32)(511 - (4*lane+0))) : 0; \
            u64 c1_ = (al8_ & 2u)   ? ((((u64)__float_as_uint(fa_.y) + 1) << 9) | (u32)(511 - (4*lane+1))) : 0; \
            u64 c2_ = (al8_ & 4u)   ? ((((u64)__float_as_uint(fa_.z) + 1) << 9) | (u32)(511 - (4*lane+2))) : 0; \
            u64 c3_ = (al8_ & 8u)   ? ((((u64)__float_as_uint(fa_.w) + 1) << 9) | (u32)(511 - (4*lane+3))) : 0; \
            u64 c4_ = (al8_ & 16u)  ? ((((u64)__float_as_uint(fb_.x) + 1) << 9) | (u32)(511 - (256+4*lane+0))) : 0; \
            u64 c5_ = (al8_ & 32u)  ? ((((u64)__float_as_uint(fb_.y) + 1) << 9) | (u32)(511 - (256+4*lane+1))) : 0; \
            u64 c6_ = (al8_ & 64u)  ? ((((u64)__float_as_uint(fb_.z) + 1) << 9) | (u32)(511 - (256+4*lane+2))) : 0; \
            u64 c7_ = (al8_ & 128u) ? ((((u64)__float_as_uint(fb_.w) + 1) << 9) | (u32)(511 - (256+4*lane+3))) : 0; \
            u64 n0_ = fm(c0_, c1_), n1_ = fm(c2_, c3_);                       \
            u64 n2_ = fm(c4_, c5_), n3_ = fm(c6_, c7_);                       \
            n0_ = fm(n0_, n1_); n2_ = fm(n2_, n3_);                           \
            u64 bw_ = fm(n0_, n2_);                                           \
            WAVE_FMAX64(bw_);                                                 \
            bw_ = readlane64(bw_, 63);                                        \
            const int wc_ = 511 - (int)(bw_ & 511);                           \
            const u32 hv_ = (u32)(bw_ >> 9);  /* val_bits+1 */                \
            if (lane == 0)                                                    \
                keys[r_] = ((u64)hv_ << 32) | ((u64)(u32)(511 - r_) << 16)    \
                         | (15ull << 9) | (u32)wc_;                           \
        }                                                                     \
    } while (0)
        if (__ballot(fb != 0)) {
            FBJ(0); FBJ(1); FBJ(2); FBJ(3); FBJ(4); FBJ(5); FBJ(6); FBJ(7);
        }

        // ---- issue next step's key reads (latency hides under stores) ----
        const ulonglong2 A = *(const ulonglong2*)&keys[2 * lane];
        const ulonglong2 Bv = *(const ulonglong2*)&keys[128 + 2 * lane];
        const ulonglong2 C = *(const ulonglong2*)&keys[256 + 2 * lane];
        const ulonglong2 D = *(const ulonglong2*)&keys[384 + 2 * lane];
        k0 = A.x;  k1 = A.y;  k2 = Bv.x; k3 = Bv.y;
        k4 = C.x;  k5 = C.y;  k6 = D.x;  k7 = D.y;

        // ---- write output row rstar (each row selected exactly once) ----
        float4 o0, o1;
        o0.x = (4 * lane + 0 == cstar) ? 1.0f : 0.0f;
        o0.y = (4 * lane + 1 == cstar) ? 1.0f : 0.0f;
        o0.z = (4 * lane + 2 == cstar) ? 1.0f : 0.0f;
        o0.w = (4 * lane + 3 == cstar) ? 1.0f : 0.0f;
        o1.x = (256 + 4 * lane + 0 == cstar) ? 1.0f : 0.0f;
        o1.y = (256 + 4 * lane + 1 == cstar) ? 1.0f : 0.0f;
        o1.z = (256 + 4 * lane + 2 == cstar) ? 1.0f : 0.0f;
        o1.w = (256 + 4 * lane + 3 == cstar) ? 1.0f : 0.0f;
        float* orow = ob + (size_t)rstar * NN;
        *(float4*)(orow + 4 * lane) = o0;
        *(float4*)(orow + 256 + 4 * lane) = o1;
    }
}

extern "C" void kernel_launch(void* const* d_in, const int* in_sizes, int n_in,
                              void* d_out, int out_size, void* d_ws, size_t ws_size,
                              hipStream_t stream) {
    const float* s = (const float*)d_in[0];
    float* out = (float*)d_out;

    build_top<<<dim3(BATCH * NN / 4), dim3(256), 0, stream>>>(s, out);
    greedy_match<<<dim3(BATCH), dim3(64), 0, stream>>>(s, out);
}